// Round 10
// baseline (115.575 us; speedup 1.0000x reference)
//
#include <hip/hip_runtime.h>
#include <hip/hip_bf16.h>
#include <cstddef>

#define BB 4
#define CC 64
#define UU 5
#define VV 5
#define HH 64
#define WW 64
#define NIJ (69*69)   // 4761

typedef float f4v __attribute__((ext_vector_type(4)));

__device__ __forceinline__ float rdlane(float v, int l) {
    return __uint_as_float((unsigned)__builtin_amdgcn_readlane((int)__float_as_uint(v), l));
}
__device__ __forceinline__ float rfl(float v) {
    return __uint_as_float((unsigned)__builtin_amdgcn_readfirstlane((int)__float_as_uint(v)));
}
__device__ __forceinline__ float sum4(float4 a) { return (a.x+a.y)+(a.z+a.w); }
__device__ __forceinline__ void nt_store4(float4 r, float4* p) {
    union { float4 s; f4v v; } u; u.s = r;
    __builtin_nontemporal_store(u.v, (f4v*)p);
}

// ---------------------------------------------------------------------------
// K1: grid = B*C*4 = 1024 blocks (bc, h-quarter), 256 threads, 4 blocks/CU.
// Thread owns quad p = qt*256+t of EVERY one of the 25 tiles ->
//   m_hw[bc][p]          final (scaled 1/25), written direct
//   m_uh[bc][u][h]       final (scaled 1/320) for the block's 16 h
//   vw_part[(bc,qt)][v][wq] f4, sum over block's 16 h (fold in k1b)
//   uv_part[(bc,qt)][k]     tile totals over block's rows (fold in k1b)
// Scratch lives in d_out (k3 rewrites it later).
// R10 fix: per-(b,c) slab stride is 25600 float4 (R9 had 6400 -> wrong slabs).
// ---------------------------------------------------------------------------
__global__ __launch_bounds__(256, 4) void k1_means(const float* __restrict__ x,
        float* __restrict__ m_hw, float* __restrict__ m_uh,
        float* __restrict__ vw_part, float* __restrict__ uv_part) {
    const int bid = blockIdx.x;       // bc*4 + qt
    const int bc  = bid >> 2;
    const int qt  = bid & 3;
    const int t   = threadIdx.x;      // 0..255
    const int p   = qt*256 + t;       // quad index in tile, 0..1023
    const int wave = t >> 6;
    const int lane = t & 63;

    const float4* xt = (const float4*)x + (size_t)bc * 25600;

    __shared__ float4 vw_lds[4][5][16];
    __shared__ float  uv_lds[4][25];

    float4 hw = make_float4(0.f,0.f,0.f,0.f);
    float4 vwacc[5];
    #pragma unroll
    for (int v = 0; v < 5; ++v) vwacc[v] = make_float4(0.f,0.f,0.f,0.f);
    float uvacc[25];

    #pragma unroll
    for (int u = 0; u < 5; ++u) {
        float uhrow = 0.f;
        #pragma unroll
        for (int v = 0; v < 5; ++v) {
            float4 q = xt[(u*5 + v)*1024 + p];
            hw.x += q.x; hw.y += q.y; hw.z += q.z; hw.w += q.w;
            vwacc[v].x += q.x; vwacc[v].y += q.y;
            vwacc[v].z += q.z; vwacc[v].w += q.w;
            float s4 = sum4(q);
            uvacc[u*5 + v] = s4;
            uhrow += s4;
        }
        // uh: sum over w = reduce over the 16-lane group covering this h-row
        float r = uhrow;
        r += __shfl_xor(r, 1); r += __shfl_xor(r, 2);
        r += __shfl_xor(r, 4); r += __shfl_xor(r, 8);
        if ((t & 15) == 0)
            m_uh[(size_t)bc*320 + u*64 + qt*16 + (t >> 4)] = r * (1.f/320.f);
    }

    // hw final, contiguous 4KB per block
    float4 o;
    o.x = hw.x*(1.f/25.f); o.y = hw.y*(1.f/25.f);
    o.z = hw.z*(1.f/25.f); o.w = hw.w*(1.f/25.f);
    ((float4*)m_hw)[(size_t)bc*1024 + p] = o;

    // vw: reduce over this wave's 4 h-rows
    #pragma unroll
    for (int v = 0; v < 5; ++v) {
        float4 s = vwacc[v];
        s.x += __shfl_xor(s.x, 16); s.y += __shfl_xor(s.y, 16);
        s.z += __shfl_xor(s.z, 16); s.w += __shfl_xor(s.w, 16);
        s.x += __shfl_xor(s.x, 32); s.y += __shfl_xor(s.y, 32);
        s.z += __shfl_xor(s.z, 32); s.w += __shfl_xor(s.w, 32);
        if (lane < 16) vw_lds[wave][v][lane] = s;
    }
    // uv: full-wave reduce of each tile total
    #pragma unroll
    for (int k = 0; k < 25; ++k) {
        float s = uvacc[k];
        s += __shfl_xor(s, 1); s += __shfl_xor(s, 2);
        s += __shfl_xor(s, 4); s += __shfl_xor(s, 8);
        s += __shfl_xor(s, 16); s += __shfl_xor(s, 32);
        if (lane == 0) uv_lds[wave][k] = s;
    }
    __syncthreads();

    if (t < 80) {     // fold 4 waves -> per-(bc,qt) vw partial
        const int v = t >> 4;
        float4 s = vw_lds[0][v][t & 15];
        #pragma unroll
        for (int w4 = 1; w4 < 4; ++w4) {
            float4 pp = vw_lds[w4][v][t & 15];
            s.x += pp.x; s.y += pp.y; s.z += pp.z; s.w += pp.w;
        }
        ((float4*)vw_part)[(size_t)bid*80 + t] = s;
    }
    if (t < 25) {     // fold 4 waves -> per-(bc,qt) uv partial
        float s = uv_lds[0][t] + uv_lds[1][t] + uv_lds[2][t] + uv_lds[3][t];
        uv_part[(size_t)bid*25 + t] = s;
    }
}

// ---------------------------------------------------------------------------
// K1b (merged): 276 blocks, 256 threads.
// blk<256: (b,h) -> transpose m_hw row + uh border.
// blk>=256: (b,v) -> fold vw/uv quarter-partials, transpose, uv border.
// ---------------------------------------------------------------------------
__global__ __launch_bounds__(256) void k1b_assemble(
        const float* __restrict__ m_hw, const float* __restrict__ m_uh,
        const float* __restrict__ vw_part, const float* __restrict__ uv_part,
        float* __restrict__ grid_t) {
    __shared__ float tile[64][68];
    const int blk = blockIdx.x;
    const bool top = blk < 256;
    const int t = threadIdx.x;        // 0..255
    const int c = t >> 2;             // 0..63
    const int qs = t & 3;             // 0..3

    int b, i;
    if (top) {
        b = blk >> 6;
        const int h = blk & 63;
        i = h;
        #pragma unroll
        for (int j = 0; j < 4; ++j) {
            const int q = 4*j + qs;   // 0..15
            float4 v = ((const float4*)m_hw)[((size_t)(b*64 + c))*1024 + h*16 + q];
            const int w = q * 4;
            tile[w+0][c] = v.x; tile[w+1][c] = v.y;
            tile[w+2][c] = v.z; tile[w+3][c] = v.w;
        }
        // uh border
        for (int idx = t; idx < 320; idx += 256) {
            const int u = idx >> 6, cc = idx & 63;
            grid_t[((size_t)b*NIJ + h*69 + 64 + u)*64 + cc] =
                m_uh[(size_t)(b*64 + cc)*320 + u*64 + h];
        }
    } else {
        b = (blk - 256) / 5;
        const int v = (blk - 256) % 5;
        i = 64 + v;
        #pragma unroll
        for (int j = 0; j < 4; ++j) {
            const int wq = 4*j + qs;
            float4 acc = make_float4(0.f,0.f,0.f,0.f);
            #pragma unroll
            for (int qt = 0; qt < 4; ++qt) {
                float4 p = ((const float4*)vw_part)
                    [((size_t)(b*64 + c)*4 + qt)*80 + v*16 + wq];
                acc.x += p.x; acc.y += p.y; acc.z += p.z; acc.w += p.w;
            }
            const int w = wq * 4;
            const float sc = 1.f/320.f;
            tile[w+0][c] = acc.x*sc; tile[w+1][c] = acc.y*sc;
            tile[w+2][c] = acc.z*sc; tile[w+3][c] = acc.w*sc;
        }
        // uv border
        for (int idx = t; idx < 320; idx += 256) {
            const int u = idx >> 6, cc = idx & 63;
            float s = 0.f;
            #pragma unroll
            for (int qt = 0; qt < 4; ++qt)
                s += uv_part[((size_t)(b*64 + cc)*4 + qt)*25 + u*5 + v];
            grid_t[((size_t)b*NIJ + i*69 + 64 + u)*64 + cc] = s * (1.f/4096.f);
        }
    }
    __syncthreads();

    float4* dst4 = (float4*)grid_t + ((size_t)b*NIJ + i*69) * 16;
    #pragma unroll
    for (int k = 0; k < 4; ++k) {
        const int oidx = k*256 + t;   // 0..1023
        const int w = oidx >> 4, cq = (oidx & 15) * 4;
        float4 v;
        v.x = tile[w][cq]; v.y = tile[w][cq+1];
        v.z = tile[w][cq+2]; v.w = tile[w][cq+3];
        dst4[oidx] = v;
    }
}

// ---------------------------------------------------------------------------
// K2: per-position MLP + region conv.
// grid = 276 rows x 4 chunks = 1104 blocks, 64 threads (one wave, ~17 cols).
// __launch_bounds__(64, 1): weight arrays stay in VGPRs (R2 lesson).
// ---------------------------------------------------------------------------
#define LOADROW(dst, src)                                              \
    { _Pragma("unroll")                                                \
      for (int q = 0; q < 16; ++q) {                                   \
          float4 t4 = ((const float4*)(src))[lane*16 + q];             \
          dst[4*q+0] = t4.x; dst[4*q+1] = t4.y;                        \
          dst[4*q+2] = t4.z; dst[4*q+3] = t4.w;                        \
      } }

#define DOT64(res, wr, src)                                            \
    float res;                                                         \
    { float _a0=0.f,_a1=0.f,_a2=0.f,_a3=0.f;                           \
      _Pragma("unroll")                                                \
      for (int cc2 = 0; cc2 < 64; cc2 += 4) {                          \
          _a0 = fmaf(wr[cc2+0], rdlane(src, cc2+0), _a0);              \
          _a1 = fmaf(wr[cc2+1], rdlane(src, cc2+1), _a1);              \
          _a2 = fmaf(wr[cc2+2], rdlane(src, cc2+2), _a2);              \
          _a3 = fmaf(wr[cc2+3], rdlane(src, cc2+3), _a3);              \
      }                                                                \
      res = (_a0 + _a1) + (_a2 + _a3); }

#define MLP_BODY(J)                                                    \
    {                                                                  \
        const int jj = (J);                                            \
        float v = gtb[(size_t)(i*69 + jj) * CC + lane];                \
        DOT64(d1, w1r, v);                                             \
        float acc1 = d1 + b1v;                                         \
        float ya = acc1 / (1.f + __expf(-acc1));                       \
        DOT64(d2, w2r, ya);                                            \
        float acc2 = d2 + b2v;                                         \
        DOT64(d3, fr, acc2);                                           \
        sp[(size_t)(jj - jbase) * sstr] = d3 + fbv;                    \
    }

__global__ __launch_bounds__(64, 1) void k2_mlp(
        const float* __restrict__ grid_t,
        const float* __restrict__ w1, const float* __restrict__ b1,
        const float* __restrict__ w2, const float* __restrict__ b2,
        const float* __restrict__ fw0, const float* __restrict__ fb0,
        const float* __restrict__ fw1, const float* __restrict__ fb1,
        const float* __restrict__ fw2, const float* __restrict__ fb2,
        const float* __restrict__ fw3, const float* __restrict__ fb3,
        float* __restrict__ mod_hw, float* __restrict__ mod_uh,
        float* __restrict__ mod_vw, float* __restrict__ mod_uv) {
    const int blk  = blockIdx.x;          // row*4 + chunk
    const int row  = blk >> 2;            // 0..275
    const int chnk = blk & 3;
    const int b    = row / 69;
    const int i    = row % 69;
    const int lane = threadIdx.x & 63;

    const int j0 = chnk * 18;
    const int j1 = min(69, j0 + 18);
    const bool top = (i < 64);

    const float* fwA = top ? fw0 : fw3;
    const float* fbA = top ? fb0 : fb3;
    const float* fwB = top ? fw2 : fw1;
    const float* fbB = top ? fb2 : fb1;

    float w1r[64], w2r[64], fr[64];
    LOADROW(w1r, w1);
    LOADROW(w2r, w2);
    const float b1v = b1[lane];
    const float b2v = b2[lane];

    const float* gtb = grid_t + (size_t)b * NIJ * CC;
    const int cbl = b * CC + lane;

    const int jm = min(j1, 64);
    if (j0 < jm) {                        // region A: j < 64
        LOADROW(fr, fwA);
        const float fbv = fbA[lane];
        float* sp; int sstr; const int jbase = 0;
        if (top) { sp = mod_hw + ((size_t)cbl*64 + i)*64;          sstr = 1; }
        else     { sp = mod_vw + (size_t)cbl*320 + (i-64)*64;      sstr = 1; }
        for (int j = j0; j < jm; ++j) MLP_BODY(j)
    }
    if (j1 > 64) {                        // region B: j >= 64
        LOADROW(fr, fwB);
        const float fbv = fbB[lane];
        float* sp; int sstr; const int jbase = 64;
        if (top) { sp = mod_uh + (size_t)cbl*320 + i;              sstr = 64; }
        else     { sp = mod_uv + (size_t)cbl*25 + (i-64);          sstr = 5;  }
        const int jb = max(j0, 64);
        for (int j = jb; j < j1; ++j) MLP_BODY(j)
    }
}

// ---------------------------------------------------------------------------
// K3: out = x * (mod_hw + mod_uv + mod_uh + mod_vw)
// 1024 blocks = (bc, quarter), 256 threads, exactly 4 blocks/CU (cap 128 VGPR;
// uv[25] forced to SGPRs via readfirstlane — loads are block-uniform).
// ---------------------------------------------------------------------------
__global__ __launch_bounds__(256, 4) void k3_apply(
        const float* __restrict__ x,
        const float* __restrict__ mod_hw, const float* __restrict__ mod_uh,
        const float* __restrict__ mod_vw, const float* __restrict__ mod_uv,
        float* __restrict__ out) {
    const int blk  = blockIdx.x;          // bc*4 + quarter
    const int bc   = blk >> 2;
    const int qt   = blk & 3;
    const int t    = threadIdx.x;         // 0..255
    const int base = qt*256 + t;          // quad index in tile, 0..1023
    const int h    = base >> 4;           // 0..63

    float4 mh = ((const float4*)(mod_hw + (size_t)bc * 4096))[base];
    float uh[5];
    #pragma unroll
    for (int u = 0; u < 5; ++u) uh[u] = mod_uh[(size_t)bc*320 + u*64 + h];
    float4 vw[5];
    #pragma unroll
    for (int v = 0; v < 5; ++v)
        vw[v] = ((const float4*)(mod_vw + (size_t)bc*320 + v*64))[t & 15];
    float uv[25];
    #pragma unroll
    for (int k = 0; k < 25; ++k)
        uv[k] = rfl(mod_uv[(size_t)bc*25 + k]);   // uniform -> SGPR

    const float4* x4 = (const float4*)(x + (size_t)bc * (UU*VV*HH*WW));
    float4* o4 = (float4*)(out + (size_t)bc * (UU*VV*HH*WW));

    #pragma unroll
    for (int u = 0; u < 5; ++u) {
        #pragma unroll
        for (int v = 0; v < 5; ++v) {
            const int idx = (u*5 + v)*1024 + base;
            float4 xv = x4[idx];
            const float s = uh[u] + uv[u*5 + v];
            float4 r;
            r.x = xv.x * (mh.x + vw[v].x + s);
            r.y = xv.y * (mh.y + vw[v].y + s);
            r.z = xv.z * (mh.z + vw[v].z + s);
            r.w = xv.w * (mh.w + vw[v].w + s);
            nt_store4(r, &o4[idx]);
        }
    }
}

// ---------------------------------------------------------------------------
extern "C" void kernel_launch(void* const* d_in, const int* in_sizes, int n_in,
                              void* d_out, int out_size, void* d_ws, size_t ws_size,
                              hipStream_t stream) {
    const float* x   = (const float*)d_in[0];
    const float* w1  = (const float*)d_in[1];
    const float* b1  = (const float*)d_in[2];
    const float* w2  = (const float*)d_in[3];
    const float* b2  = (const float*)d_in[4];
    const float* fw0 = (const float*)d_in[5];
    const float* fb0 = (const float*)d_in[6];
    const float* fw1 = (const float*)d_in[7];
    const float* fb1 = (const float*)d_in[8];
    const float* fw2 = (const float*)d_in[9];
    const float* fb2 = (const float*)d_in[10];
    const float* fw3 = (const float*)d_in[11];
    const float* fb3 = (const float*)d_in[12];

    float* ws = (float*)d_ws;
    float* grid_t = ws;                        // 4*4761*64      = 1,218,816
    float* mod_hw = ws + 1218816;              // 256*4096       = 1,048,576
    float* mod_uh = mod_hw + 1048576;          // 256*320        =    81,920
    float* mod_vw = mod_uh + 81920;            // 256*320        =    81,920
    float* mod_uv = mod_vw + 81920;            // 256*25         =     6,400

    // d_out doubles as scratch for k1 outputs (k3 fully rewrites it).
    float* m_hw    = (float*)d_out;            // 256*4096       = 1,048,576
    float* m_uh    = m_hw + 1048576;           // 256*320        =    81,920
    float* vw_part = m_uh + 81920;             // 1024*80*4      =   327,680
    float* uv_part = vw_part + 327680;         // 1024*25        =    25,600

    k1_means<<<BB*CC*4, 256, 0, stream>>>(x, m_hw, m_uh, vw_part, uv_part);
    k1b_assemble<<<BB*CC + BB*VV, 256, 0, stream>>>(m_hw, m_uh, vw_part, uv_part, grid_t);
    k2_mlp<<<BB*69*4, 64, 0, stream>>>(grid_t, w1, b1, w2, b2,
                                       fw0, fb0, fw1, fb1, fw2, fb2, fw3, fb3,
                                       mod_hw, mod_uh, mod_vw, mod_uv);
    k3_apply<<<BB*CC*4, 256, 0, stream>>>(x, mod_hw, mod_uh, mod_vw, mod_uv,
                                          (float*)d_out);
}